// Round 6
// baseline (613.588 us; speedup 1.0000x reference)
//
#include <hip/hip_runtime.h>

// Problem constants (fixed by the reference)
#define NN 200000   // nodes
#define CC 256      // channels
#define NG 512      // graphs/segments

typedef __attribute__((ext_vector_type(8))) __bf16 bf16x8;
typedef __attribute__((ext_vector_type(16))) float f32x16;

__device__ __forceinline__ unsigned short f2bf(float f) {
  union { float f; unsigned u; } v; v.f = f;
  unsigned u = v.u;
  u += 0x7fffu + ((u >> 16) & 1u);   // RNE
  return (unsigned short)(u >> 16);
}
__device__ __forceinline__ unsigned pack2(float a, float b) {
  return (unsigned)f2bf(a) | ((unsigned)f2bf(b) << 16);
}
__device__ __forceinline__ float bflo(unsigned u){ union{unsigned u; float f;} x; x.u = u << 16; return x.f; }
__device__ __forceinline__ float bfhi(unsigned u){ union{unsigned u; float f;} x; x.u = u & 0xffff0000u; return x.f; }

// ---------------------------------------------------------------------------
// K0: prep all weights into 32x32x16 MFMA *A-operand* fragment order for the
// transposed GEMM  C^T[dim][node] = W^T[dim][k] * x^T[k][node].
//  Wall slice s (16 KB each): A[row r = (s%8)*32 + (l&31)][k = ks*16+(l>>5)*8+j]
//  flat idx = s*8192 + ks*512 + l*8 + j.  Slices: 0-7 Wv, 8-15 Wk, 16-23 Wq,
//  24-31 Wo.   (unchanged from R4/R5 — numerically proven)
// ---------------------------------------------------------------------------
__global__ __launch_bounds__(256) void prep_kernel(
    const float* __restrict__ Wq, const float* __restrict__ Wk,
    const float* __restrict__ Wv, const float* __restrict__ Wo,
    unsigned short* __restrict__ Wall) {
  int idx = blockIdx.x * 256 + threadIdx.x;     // 0..262143
  int s = idx >> 13;
  int inner = idx & 8191;
  int ks = inner >> 9;
  int l = (inner >> 3) & 63;
  int j = inner & 7;
  int r = l & 31, hi5 = l >> 5;
  int k = ks * 16 + hi5 * 8 + j;
  const float* W;
  int c;
  if (s < 8)       { W = Wv; c = s * 32 + r; }
  else if (s < 16) { W = Wk; c = (s - 8) * 32 + r; }
  else if (s < 24) { W = Wq; c = (s - 16) * 32 + r; }
  else             { W = Wo; c = (s - 24) * 32 + r; }
  Wall[idx] = f2bf(W[k * 256 + c]);
}

// ---------------------------------------------------------------------------
// K1: segment boundaries from sorted batch.
// ---------------------------------------------------------------------------
__global__ __launch_bounds__(256) void seg_bounds_kernel(
    const int* __restrict__ batch, int* __restrict__ seg_start, int n) {
  int i = blockIdx.x * 256 + threadIdx.x;
  if (i >= n) return;
  int a = batch[i];
  int b = (i + 1 < n) ? batch[i + 1] : NG;
  for (int g = a + 1; g <= b; ++g) seg_start[g] = i + 1;
  if (i == 0) for (int g = 0; g <= a; ++g) seg_start[g] = 0;
}

// ---------------------------------------------------------------------------
// One 32(dims)x32(nodes) slice over K=256: 16 MFMAs.  A = W-frags streamed
// from L2 (independent loads, register-buffered); B = x-frags in registers.
// ---------------------------------------------------------------------------
__device__ __forceinline__ f32x16 gemm32(const bf16x8 xb[16],
    const unsigned short* __restrict__ Wall, int slice, int lane) {
  const unsigned short* wp = Wall + slice * 8192 + lane * 8;
  f32x16 acc = {0.f, 0.f, 0.f, 0.f, 0.f, 0.f, 0.f, 0.f,
                0.f, 0.f, 0.f, 0.f, 0.f, 0.f, 0.f, 0.f};
#pragma unroll
  for (int ks = 0; ks < 16; ++ks) {
    bf16x8 af = *reinterpret_cast<const bf16x8*>(wp + ks * 512);
    acc = __builtin_amdgcn_mfma_f32_32x32x16_bf16(af, xb[ks], acc, 0, 0, 0);
  }
  return acc;
}

// ---------------------------------------------------------------------------
// K2: fused QKV + scores.  256 threads = 4 waves, BM=64 nodes, ONE barrier.
//  LDS At (32 KB): x bf16 in B-frag layout, XOR-swizzled (l' = l ^ ks) so both
//  staging ds_write_b128 and frag ds_read_b128 are bank-conflict-free.
//  Wave roles: wid 0,1 -> QK+scores for node-tile wid; wid 2,3 -> V for
//  node-tile wid-2.  After the barrier each wave preloads its 16 x-frags
//  (64 VGPR) and free-runs on the L2 W-stream.
// ---------------------------------------------------------------------------
__global__ __launch_bounds__(256, 2) void qkv_scores_kernel(
    const float* __restrict__ x, const unsigned short* __restrict__ Wall,
    const float* __restrict__ bq, const float* __restrict__ bk,
    const float* __restrict__ bv,
    unsigned short* __restrict__ v_out,   // [NN][256] bf16
    float* __restrict__ scores) {         // [NN][16]
  __shared__ unsigned short At[16384];    // ((nt*16+ks)*64 + ((hi*32+node)^ks))*8 + j

  const int t = threadIdx.x;
  const int r0 = blockIdx.x * 64;

  // ---- stage x (64 rows x 256) fp32 -> bf16 frag layout, swizzled ----
#pragma unroll
  for (int i = 0; i < 8; ++i) {
    int u = i * 256 + t;
    int r = u >> 5;            // 0..63
    int c = (u & 31) * 8;      // 0..248
    const float* px = x + (size_t)(r0 + r) * CC + c;
    float4 a0 = *reinterpret_cast<const float4*>(px);
    float4 a1 = *reinterpret_cast<const float4*>(px + 4);
    uint4 pk = {pack2(a0.x, a0.y), pack2(a0.z, a0.w),
                pack2(a1.x, a1.y), pack2(a1.z, a1.w)};
    int ntile = r >> 5, node = r & 31, ks = c >> 4, hi = (c >> 3) & 1;
    int l = (hi * 32 + node) ^ ks;
    *reinterpret_cast<uint4*>(&At[((ntile * 16 + ks) * 64 + l) * 8]) = pk;
  }
  __syncthreads();

  const int wid = t >> 6;
  const int lane = t & 63;
  const int nt = wid & 1;
  const int col = lane & 31, hi5 = lane >> 5;
  const int n = r0 + nt * 32 + col;

  // ---- preload this node-tile's 16 x-frags (64 VGPR) ----
  bf16x8 xfr[16];
#pragma unroll
  for (int ks = 0; ks < 16; ++ks)
    xfr[ks] = *reinterpret_cast<const bf16x8*>(
        &At[((nt * 16 + ks) * 64 + (lane ^ ks)) * 8]);

  if (wid >= 2) {
    // ---- V role: slices 0..7 -> packed 8B stores, row-major v_out ----
#pragma unroll 1
    for (int s = 0; s < 8; ++s) {
      f32x16 acc = gemm32(xfr, Wall, s, lane);
#pragma unroll
      for (int q = 0; q < 4; ++q) {
        int d0 = s * 32 + q * 8 + hi5 * 4;
        float4 b4 = *reinterpret_cast<const float4*>(bv + d0);
        uint2 pk = {pack2(acc[4 * q] + b4.x, acc[4 * q + 1] + b4.y),
                    pack2(acc[4 * q + 2] + b4.z, acc[4 * q + 3] + b4.w)};
        *reinterpret_cast<uint2*>(v_out + (size_t)n * CC + d0) = pk;
      }
    }
  } else {
    // ---- QK role: K then Q, split by half-head-dim p; in-lane fold ----
    float sp[16];
#pragma unroll
    for (int i = 0; i < 16; ++i) sp[i] = 0.f;

#pragma unroll 1
    for (int p = 0; p < 2; ++p) {
      unsigned kph[4][8];      // k, packed bf16, head g, this half (32 VGPR)
#pragma unroll
      for (int g = 0; g < 4; ++g) {
        f32x16 acc = gemm32(xfr, Wall, 8 + 2 * g + p, lane);
#pragma unroll
        for (int q = 0; q < 4; ++q) {
          float4 b4 = *reinterpret_cast<const float4*>(
              bk + (2 * g + p) * 32 + q * 8 + hi5 * 4);
          kph[g][q * 2]     = pack2(acc[4 * q] + b4.x, acc[4 * q + 1] + b4.y);
          kph[g][q * 2 + 1] = pack2(acc[4 * q + 2] + b4.z, acc[4 * q + 3] + b4.w);
        }
      }
#pragma unroll
      for (int h = 0; h < 4; ++h) {
        f32x16 acc = gemm32(xfr, Wall, 16 + 2 * h + p, lane);
#pragma unroll
        for (int q = 0; q < 4; ++q) {
          float4 b4 = *reinterpret_cast<const float4*>(
              bq + (2 * h + p) * 32 + q * 8 + hi5 * 4);
          float q0 = acc[4 * q] + b4.x, q1 = acc[4 * q + 1] + b4.y;
          float q2 = acc[4 * q + 2] + b4.z, q3 = acc[4 * q + 3] + b4.w;
#pragma unroll
          for (int g = 0; g < 4; ++g) {
            unsigned k01 = kph[g][q * 2];
            unsigned k23 = kph[g][q * 2 + 1];
            sp[h * 4 + g] += q0 * bflo(k01) + q1 * bfhi(k01) +
                             q2 * bflo(k23) + q3 * bfhi(k23);
          }
        }
      }
    }

#pragma unroll
    for (int i = 0; i < 16; ++i) sp[i] += __shfl_xor(sp[i], 32, 64);
    if (hi5 == 0) {
#pragma unroll
      for (int q = 0; q < 4; ++q) {
        float4 o = {sp[q * 4] * 0.125f, sp[q * 4 + 1] * 0.125f,
                    sp[q * 4 + 2] * 0.125f, sp[q * 4 + 3] * 0.125f};
        *reinterpret_cast<float4*>(scores + (size_t)n * 16 + q * 4) = o;
      }
    }
  }
}

// ---------------------------------------------------------------------------
// K3: per-segment max & exp-sum over the 16 score columns (block per segment).
// ---------------------------------------------------------------------------
__global__ __launch_bounds__(256) void seg_softmax_kernel(
    const float* __restrict__ scores, const int* __restrict__ seg_start,
    float* __restrict__ seg_max, float* __restrict__ seg_sum) {
  __shared__ float red[256];
  int g = blockIdx.x;
  int s = seg_start[g], e = seg_start[g + 1];
  int t = threadIdx.x;
  int col = t & 15, sub = t >> 4;

  float m = -INFINITY;
  for (int i = s + sub; i < e; i += 16)
    m = fmaxf(m, scores[(size_t)i * 16 + col]);
  red[t] = m;
  __syncthreads();
  for (int step = 8; step >= 1; step >>= 1) {
    if (sub < step) red[t] = fmaxf(red[t], red[t + step * 16]);
    __syncthreads();
  }
  if (t < 16) seg_max[g * 16 + t] = red[t];
  float mcol = red[col];
  __syncthreads();

  float sum = 0.f;
  for (int i = s + sub; i < e; i += 16)
    sum += expf(scores[(size_t)i * 16 + col] - mcol);
  red[t] = sum;
  __syncthreads();
  for (int step = 8; step >= 1; step >>= 1) {
    if (sub < step) red[t] += red[t + step * 16];
    __syncthreads();
  }
  if (t < 16) seg_sum[g * 16 + t] = red[t];
}

// ---------------------------------------------------------------------------
// K4: fused att + att.v + output GEMM (+bo) + att_mean.  256 threads =
//     4 waves: (node-tile nt, slice-half sh).  Zero LDS, zero barriers.
//     Both waves of a node-tile build att+oaf (cheap, L2-hot); each does
//     4 of the 8 Wo slices.
// ---------------------------------------------------------------------------
__global__ __launch_bounds__(256, 2) void out_kernel(
    const unsigned short* __restrict__ v_bf, const float* __restrict__ scores,
    const int* __restrict__ batch, const float* __restrict__ seg_max,
    const float* __restrict__ seg_sum, const unsigned short* __restrict__ Wall,
    const float* __restrict__ bo, float* __restrict__ out,
    float* __restrict__ att_mean) {
  const int t = threadIdx.x;
  const int wid = t >> 6;
  const int lane = t & 63;
  const int nt = wid & 1, sh = wid >> 1;
  const int col = lane & 31, hi5 = lane >> 5;
  const int n = blockIdx.x * 64 + nt * 32 + col;

  // ---- att[16] for this lane's node ----
  int b = batch[n];
  float att[16];
#pragma unroll
  for (int q = 0; q < 4; ++q) {
    float4 sc = *reinterpret_cast<const float4*>(scores + (size_t)n * 16 + q * 4);
    float4 mx = *reinterpret_cast<const float4*>(seg_max + b * 16 + q * 4);
    float4 sm = *reinterpret_cast<const float4*>(seg_sum + b * 16 + q * 4);
    att[q * 4 + 0] = expf(sc.x - mx.x) / (sm.x + 1e-16f);
    att[q * 4 + 1] = expf(sc.y - mx.y) / (sm.y + 1e-16f);
    att[q * 4 + 2] = expf(sc.z - mx.z) / (sm.z + 1e-16f);
    att[q * 4 + 3] = expf(sc.w - mx.w) / (sm.w + 1e-16f);
  }
  if (sh == 0 && hi5 == 0) {
    float4 am;
    am.x = 0.25f * (att[0] + att[4] + att[8] + att[12]);
    am.y = 0.25f * (att[1] + att[5] + att[9] + att[13]);
    am.z = 0.25f * (att[2] + att[6] + att[10] + att[14]);
    am.w = 0.25f * (att[3] + att[7] + att[11] + att[15]);
    *reinterpret_cast<float4*>(att_mean + (size_t)n * 4) = am;
  }

  // ---- oa^T B-frags: oa[n][h*64+dd] = sum_g att[h*4+g]*v[n][g*64+dd] ----
  bf16x8 oaf[16];
#pragma unroll
  for (int dw = 0; dw < 4; ++dw) {
    int dd = dw * 16 + hi5 * 8;
    float vr[4][8];
#pragma unroll
    for (int g = 0; g < 4; ++g) {
      uint4 vv = *reinterpret_cast<const uint4*>(
          v_bf + (size_t)n * CC + g * 64 + dd);
      vr[g][0] = bflo(vv.x); vr[g][1] = bfhi(vv.x);
      vr[g][2] = bflo(vv.y); vr[g][3] = bfhi(vv.y);
      vr[g][4] = bflo(vv.z); vr[g][5] = bfhi(vv.z);
      vr[g][6] = bflo(vv.w); vr[g][7] = bfhi(vv.w);
    }
#pragma unroll
    for (int h = 0; h < 4; ++h) {
      unsigned res[4];
#pragma unroll
      for (int jj = 0; jj < 4; ++jj) {
        float lo = att[h * 4 + 0] * vr[0][2 * jj] + att[h * 4 + 1] * vr[1][2 * jj] +
                   att[h * 4 + 2] * vr[2][2 * jj] + att[h * 4 + 3] * vr[3][2 * jj];
        float hf = att[h * 4 + 0] * vr[0][2 * jj + 1] + att[h * 4 + 1] * vr[1][2 * jj + 1] +
                   att[h * 4 + 2] * vr[2][2 * jj + 1] + att[h * 4 + 3] * vr[3][2 * jj + 1];
        res[jj] = pack2(lo, hf);
      }
      uint4 u = {res[0], res[1], res[2], res[3]};
      oaf[h * 4 + dw] = *reinterpret_cast<bf16x8*>(&u);
    }
  }

  // ---- output GEMM: this wave's 4 Wo slices; D[c][n]; float4 stores ----
#pragma unroll 1
  for (int s2 = 0; s2 < 4; ++s2) {
    int sl = sh * 4 + s2;
    f32x16 acc = gemm32(oaf, Wall, 24 + sl, lane);
#pragma unroll
    for (int q = 0; q < 4; ++q) {
      int c0 = sl * 32 + q * 8 + hi5 * 4;
      float4 b4 = *reinterpret_cast<const float4*>(bo + c0);
      float4 o = {acc[4 * q] + b4.x, acc[4 * q + 1] + b4.y,
                  acc[4 * q + 2] + b4.z, acc[4 * q + 3] + b4.w};
      *reinterpret_cast<float4*>(out + (size_t)n * CC + c0) = o;
    }
  }
}

// ---------------------------------------------------------------------------
extern "C" void kernel_launch(void* const* d_in, const int* in_sizes, int n_in,
                              void* d_out, int out_size, void* d_ws, size_t ws_size,
                              hipStream_t stream) {
  const float* x  = (const float*)d_in[0];
  const int* batch = (const int*)d_in[1];
  const float* Wq = (const float*)d_in[2];
  const float* bq = (const float*)d_in[3];
  const float* Wk = (const float*)d_in[4];
  const float* bk = (const float*)d_in[5];
  const float* Wv = (const float*)d_in[6];
  const float* bv = (const float*)d_in[7];
  const float* Wo = (const float*)d_in[8];
  const float* bo = (const float*)d_in[9];

  char* ws = (char*)d_ws;
  unsigned short* Wall = (unsigned short*)ws;                //   524,288 B (32 slices)
  int*   seg_start = (int*)(ws + 524288);                    //     2,052 B
  float* seg_max   = (float*)(ws + 528384);                  //    32,768 B
  float* seg_sum   = (float*)(ws + 561152);                  //    32,768 B
  float* scores    = (float*)(ws + 593920);                  // 12,800,000 B
  unsigned short* v_bf = (unsigned short*)(ws + 13393920);   // 102,400,000 B

  float* out = (float*)d_out;
  float* att_mean = out + (size_t)NN * CC;

  prep_kernel<<<1024, 256, 0, stream>>>(Wq, Wk, Wv, Wo, Wall);
  seg_bounds_kernel<<<(NN + 255) / 256, 256, 0, stream>>>(batch, seg_start, NN);
  qkv_scores_kernel<<<NN / 64, 256, 0, stream>>>(x, Wall, bq, bk, bv, v_bf, scores);
  seg_softmax_kernel<<<NG, 256, 0, stream>>>(scores, seg_start, seg_max, seg_sum);
  out_kernel<<<NN / 64, 256, 0, stream>>>(v_bf, scores, batch, seg_max, seg_sum,
                                          Wall, bo, out, att_mean);
}

// Round 7
// 290.414 us; speedup vs baseline: 2.1128x; 2.1128x over previous
//
#include <hip/hip_runtime.h>

// Problem constants (fixed by the reference)
#define NN 200000   // nodes
#define CC 256      // channels
#define NG 512      // graphs/segments

typedef __attribute__((ext_vector_type(8))) __bf16 bf16x8;
typedef __attribute__((ext_vector_type(16))) float f32x16;

typedef unsigned short u16;

__device__ __forceinline__ u16 f2bf(float f) {
  union { float f; unsigned u; } v; v.f = f;
  unsigned u = v.u;
  u += 0x7fffu + ((u >> 16) & 1u);   // RNE
  return (u16)(u >> 16);
}
__device__ __forceinline__ unsigned pack2(float a, float b) {
  return (unsigned)f2bf(a) | ((unsigned)f2bf(b) << 16);
}
__device__ __forceinline__ float bflo(unsigned u){ union{unsigned u; float f;} x; x.u = u << 16; return x.f; }
__device__ __forceinline__ float bfhi(unsigned u){ union{unsigned u; float f;} x; x.u = u & 0xffff0000u; return x.f; }

// ---------------------------------------------------------------------------
// K0: prep weights into 32x32x16 MFMA A-operand fragment slices (16 KB each).
//  Slice order (dims per slice = 32):
//   0..3   K heads 0..3, even half (dims g*64 + 0..31)
//   4..7   Q heads 0..3, even half
//   8..11  K heads 0..3, odd half  (dims g*64 + 32..63)
//   12..15 Q heads 0..3, odd half
//   16..23 V (dims sv*32..)
//   24..31 Wo (dims so*32..)
//  Element (s, ks, l, j) at flat idx s*8192 + ks*512 + l*8 + j holds
//   W[k = ks*16 + (l>>5)*8 + j][c0(s) + (l&31)]  (A-frag: row=l&31, verified R4)
// ---------------------------------------------------------------------------
__global__ __launch_bounds__(256) void prep_kernel(
    const float* __restrict__ Wq, const float* __restrict__ Wk,
    const float* __restrict__ Wv, const float* __restrict__ Wo,
    u16* __restrict__ Wall) {
  int idx = blockIdx.x * 256 + threadIdx.x;     // 0..262143
  int s = idx >> 13;
  int inner = idx & 8191;
  int ks = inner >> 9;
  int l = (inner >> 3) & 63;
  int j = inner & 7;
  int r = l & 31, hi5 = l >> 5;
  int k = ks * 16 + hi5 * 8 + j;
  const float* W; int c0;
  if (s < 16) {
    int p = s >> 3, r4 = s & 7;
    if (r4 < 4) { W = Wk; c0 = r4 * 64 + p * 32; }
    else        { W = Wq; c0 = (r4 - 4) * 64 + p * 32; }
  } else if (s < 24) { W = Wv; c0 = (s - 16) * 32; }
  else               { W = Wo; c0 = (s - 24) * 32; }
  Wall[idx] = f2bf(W[k * 256 + c0 + r]);
}

// ---------------------------------------------------------------------------
// K1: segment boundaries from sorted batch.
// ---------------------------------------------------------------------------
__global__ __launch_bounds__(256) void seg_bounds_kernel(
    const int* __restrict__ batch, int* __restrict__ seg_start, int n) {
  int i = blockIdx.x * 256 + threadIdx.x;
  if (i >= n) return;
  int a = batch[i];
  int b = (i + 1 < n) ? batch[i + 1] : NG;
  for (int g = a + 1; g <= b; ++g) seg_start[g] = i + 1;
  if (i == 0) for (int g = 0; g <= a; ++g) seg_start[g] = 0;
}

// ---------------------------------------------------------------------------
// Stage one 16 KB W slice into LDS: 256 threads x 4 reps x 16 B, linear dest
// (global_load_lds: wave-uniform LDS base + lane*16).
// ---------------------------------------------------------------------------
__device__ __forceinline__ void stage_slice(
    const u16* __restrict__ Wall, u16* dst_base, int s, int w, int lane) {
#pragma unroll
  for (int rep = 0; rep < 4; ++rep) {
    const u16* src = Wall + (size_t)s * 8192 + ((w * 4 + rep) * 64 + lane) * 8;
    u16* dst = dst_base + (w * 4 + rep) * 512;
    __builtin_amdgcn_global_load_lds(
        (const __attribute__((address_space(1))) void*)src,
        (__attribute__((address_space(3))) void*)dst, 16, 0, 0);
  }
}

// ---------------------------------------------------------------------------
// One 32(dims)x32(nodes) slice over K=256: A-frags from LDS (16 ds_read_b128),
// B (x) from registers.  Two accumulator chains to break MFMA dependency.
// ---------------------------------------------------------------------------
__device__ __forceinline__ f32x16 gemm_lds(
    const u16* buf, const bf16x8 xfr[16], int lane) {
  f32x16 a0 = {0.f,0.f,0.f,0.f,0.f,0.f,0.f,0.f,0.f,0.f,0.f,0.f,0.f,0.f,0.f,0.f};
  f32x16 a1 = a0;
#pragma unroll
  for (int ks = 0; ks < 16; ks += 2) {
    bf16x8 f0 = *reinterpret_cast<const bf16x8*>(&buf[(ks * 64 + lane) * 8]);
    bf16x8 f1 = *reinterpret_cast<const bf16x8*>(&buf[((ks + 1) * 64 + lane) * 8]);
    a0 = __builtin_amdgcn_mfma_f32_32x32x16_bf16(f0, xfr[ks], a0, 0, 0, 0);
    a1 = __builtin_amdgcn_mfma_f32_32x32x16_bf16(f1, xfr[ks + 1], a1, 0, 0, 0);
  }
  return a0 + a1;
}

// ---------------------------------------------------------------------------
// K2: fused QKV + scores.  256 threads = 4 waves x 32 nodes = 128 nodes/block.
//  24 slices staged block-wide into double-buffered LDS (one barrier/slice);
//  x^T B-frags persistent in regs; q.k folded in-lane (D col=lane&31=node),
//  shfl_xor(32) completes the 64-dim dot.
// ---------------------------------------------------------------------------
__global__ __launch_bounds__(256, 2) void qkv_scores_kernel(
    const float* __restrict__ x, const u16* __restrict__ Wall,
    const float* __restrict__ bq, const float* __restrict__ bk,
    const float* __restrict__ bv,
    u16* __restrict__ v_out,              // [NN][256] bf16
    float* __restrict__ scores) {         // [NN][16]
  __shared__ u16 Wbuf[2][8192];

  const int t = threadIdx.x;
  const int w = t >> 6, lane = t & 63;
  const int col = lane & 31, hi5 = lane >> 5;
  const int n = blockIdx.x * 128 + w * 32 + col;
  const int nl = (n < NN) ? n : (NN - 1);
  const bool valid = (n < NN);

  stage_slice(Wall, Wbuf[0], 0, w, lane);

  // ---- B-frags: x^T, persistent (64 VGPR). frag kb: k = kb*16+hi5*8+j ----
  bf16x8 xfr[16];
#pragma unroll
  for (int kb = 0; kb < 16; ++kb) {
    const float* px = x + (size_t)nl * CC + kb * 16 + hi5 * 8;
    float4 a0 = *reinterpret_cast<const float4*>(px);
    float4 a1 = *reinterpret_cast<const float4*>(px + 4);
    uint4 u = {pack2(a0.x, a0.y), pack2(a0.z, a0.w),
               pack2(a1.x, a1.y), pack2(a1.z, a1.w)};
    xfr[kb] = *reinterpret_cast<bf16x8*>(&u);
  }
  __syncthreads();   // Wbuf[0] ready (syncthreads drains vmcnt)

  // ---- K/Q phases: slices 0..15, in-lane fold ----
  float sp[16];
#pragma unroll
  for (int i = 0; i < 16; ++i) sp[i] = 0.f;

#pragma unroll 1
  for (int p = 0; p < 2; ++p) {
    unsigned kph[4][8];          // k packed bf16, head g, this half
#pragma unroll
    for (int g = 0; g < 4; ++g) {
      stage_slice(Wall, Wbuf[(g + 1) & 1], p * 8 + g + 1, w, lane);
      f32x16 acc = gemm_lds(Wbuf[g & 1], xfr, lane);
#pragma unroll
      for (int q = 0; q < 4; ++q) {
        float4 b4 = *reinterpret_cast<const float4*>(
            bk + g * 64 + p * 32 + q * 8 + hi5 * 4);
        kph[g][q * 2]     = pack2(acc[4 * q] + b4.x, acc[4 * q + 1] + b4.y);
        kph[g][q * 2 + 1] = pack2(acc[4 * q + 2] + b4.z, acc[4 * q + 3] + b4.w);
      }
      __syncthreads();
    }
#pragma unroll
    for (int h = 0; h < 4; ++h) {
      // next slice: p*8+4+h+1; for p=1,h=3 -> slice 16 (first V) -- always <24
      stage_slice(Wall, Wbuf[(h + 1) & 1], p * 8 + 5 + h, w, lane);
      f32x16 acc = gemm_lds(Wbuf[h & 1], xfr, lane);
#pragma unroll
      for (int q = 0; q < 4; ++q) {
        float4 b4 = *reinterpret_cast<const float4*>(
            bq + h * 64 + p * 32 + q * 8 + hi5 * 4);
        float q0 = acc[4 * q] + b4.x, q1 = acc[4 * q + 1] + b4.y;
        float q2 = acc[4 * q + 2] + b4.z, q3 = acc[4 * q + 3] + b4.w;
#pragma unroll
        for (int g = 0; g < 4; ++g) {
          unsigned k01 = kph[g][q * 2];
          unsigned k23 = kph[g][q * 2 + 1];
          sp[h * 4 + g] += q0 * bflo(k01) + q1 * bfhi(k01) +
                           q2 * bflo(k23) + q3 * bfhi(k23);
        }
      }
      __syncthreads();
    }
  }

#pragma unroll
  for (int i = 0; i < 16; ++i) sp[i] += __shfl_xor(sp[i], 32, 64);
  if (hi5 == 0 && valid) {
#pragma unroll
    for (int q = 0; q < 4; ++q) {
      float4 o = {sp[q * 4] * 0.125f, sp[q * 4 + 1] * 0.125f,
                  sp[q * 4 + 2] * 0.125f, sp[q * 4 + 3] * 0.125f};
      *reinterpret_cast<float4*>(scores + (size_t)n * 16 + q * 4) = o;
    }
  }

  // ---- V phase: slices 16..23 ----
#pragma unroll
  for (int sv = 0; sv < 8; ++sv) {
    if (sv < 7) stage_slice(Wall, Wbuf[(sv + 1) & 1], 17 + sv, w, lane);
    f32x16 acc = gemm_lds(Wbuf[sv & 1], xfr, lane);
    if (valid) {
#pragma unroll
      for (int q = 0; q < 4; ++q) {
        int d0 = sv * 32 + q * 8 + hi5 * 4;
        float4 b4 = *reinterpret_cast<const float4*>(bv + d0);
        uint2 pk = {pack2(acc[4 * q] + b4.x, acc[4 * q + 1] + b4.y),
                    pack2(acc[4 * q + 2] + b4.z, acc[4 * q + 3] + b4.w)};
        *reinterpret_cast<uint2*>(v_out + (size_t)n * CC + d0) = pk;
      }
    }
    __syncthreads();
  }
}

// ---------------------------------------------------------------------------
// K3: per-segment max & exp-sum over the 16 score columns (block per segment).
// ---------------------------------------------------------------------------
__global__ __launch_bounds__(256) void seg_softmax_kernel(
    const float* __restrict__ scores, const int* __restrict__ seg_start,
    float* __restrict__ seg_max, float* __restrict__ seg_sum) {
  __shared__ float red[256];
  int g = blockIdx.x;
  int s = seg_start[g], e = seg_start[g + 1];
  int t = threadIdx.x;
  int col = t & 15, sub = t >> 4;

  float m = -INFINITY;
  for (int i = s + sub; i < e; i += 16)
    m = fmaxf(m, scores[(size_t)i * 16 + col]);
  red[t] = m;
  __syncthreads();
  for (int step = 8; step >= 1; step >>= 1) {
    if (sub < step) red[t] = fmaxf(red[t], red[t + step * 16]);
    __syncthreads();
  }
  if (t < 16) seg_max[g * 16 + t] = red[t];
  float mcol = red[col];
  __syncthreads();

  float sum = 0.f;
  for (int i = s + sub; i < e; i += 16)
    sum += expf(scores[(size_t)i * 16 + col] - mcol);
  red[t] = sum;
  __syncthreads();
  for (int step = 8; step >= 1; step >>= 1) {
    if (sub < step) red[t] += red[t + step * 16];
    __syncthreads();
  }
  if (t < 16) seg_sum[g * 16 + t] = red[t];
}

// ---------------------------------------------------------------------------
// K4: fused att + att.v + output GEMM (+bo) + att_mean.  Same block shape as
//     K2: 4 waves x 32 nodes; Wo slices 24..31 staged via double-buffered LDS.
// ---------------------------------------------------------------------------
__global__ __launch_bounds__(256, 2) void out_kernel(
    const u16* __restrict__ v_bf, const float* __restrict__ scores,
    const int* __restrict__ batch, const float* __restrict__ seg_max,
    const float* __restrict__ seg_sum, const u16* __restrict__ Wall,
    const float* __restrict__ bo, float* __restrict__ out,
    float* __restrict__ att_mean) {
  __shared__ u16 Wbuf[2][8192];

  const int t = threadIdx.x;
  const int w = t >> 6, lane = t & 63;
  const int col = lane & 31, hi5 = lane >> 5;
  const int n = blockIdx.x * 128 + w * 32 + col;
  const int nl = (n < NN) ? n : (NN - 1);
  const bool valid = (n < NN);

  stage_slice(Wall, Wbuf[0], 24, w, lane);

  // ---- att[16] for this lane's node ----
  int b = batch[nl];
  float att[16];
#pragma unroll
  for (int q = 0; q < 4; ++q) {
    float4 sc = *reinterpret_cast<const float4*>(scores + (size_t)nl * 16 + q * 4);
    float4 mx = *reinterpret_cast<const float4*>(seg_max + b * 16 + q * 4);
    float4 sm = *reinterpret_cast<const float4*>(seg_sum + b * 16 + q * 4);
    att[q * 4 + 0] = expf(sc.x - mx.x) / (sm.x + 1e-16f);
    att[q * 4 + 1] = expf(sc.y - mx.y) / (sm.y + 1e-16f);
    att[q * 4 + 2] = expf(sc.z - mx.z) / (sm.z + 1e-16f);
    att[q * 4 + 3] = expf(sc.w - mx.w) / (sm.w + 1e-16f);
  }
  if (hi5 == 0 && valid) {
    float4 am;
    am.x = 0.25f * (att[0] + att[4] + att[8] + att[12]);
    am.y = 0.25f * (att[1] + att[5] + att[9] + att[13]);
    am.z = 0.25f * (att[2] + att[6] + att[10] + att[14]);
    am.w = 0.25f * (att[3] + att[7] + att[11] + att[15]);
    *reinterpret_cast<float4*>(att_mean + (size_t)n * 4) = am;
  }

  // ---- oa^T B-frags: oa[n][h*64+dd] = sum_g att[h*4+g]*v[n][g*64+dd] ----
  bf16x8 oaf[16];
#pragma unroll
  for (int dw = 0; dw < 4; ++dw) {
    int dd = dw * 16 + hi5 * 8;
    float vr[4][8];
#pragma unroll
    for (int g = 0; g < 4; ++g) {
      uint4 vv = *reinterpret_cast<const uint4*>(
          v_bf + (size_t)nl * CC + g * 64 + dd);
      vr[g][0] = bflo(vv.x); vr[g][1] = bfhi(vv.x);
      vr[g][2] = bflo(vv.y); vr[g][3] = bfhi(vv.y);
      vr[g][4] = bflo(vv.z); vr[g][5] = bfhi(vv.z);
      vr[g][6] = bflo(vv.w); vr[g][7] = bfhi(vv.w);
    }
#pragma unroll
    for (int h = 0; h < 4; ++h) {
      unsigned res[4];
#pragma unroll
      for (int jj = 0; jj < 4; ++jj) {
        float lo = att[h * 4 + 0] * vr[0][2 * jj] + att[h * 4 + 1] * vr[1][2 * jj] +
                   att[h * 4 + 2] * vr[2][2 * jj] + att[h * 4 + 3] * vr[3][2 * jj];
        float hf = att[h * 4 + 0] * vr[0][2 * jj + 1] + att[h * 4 + 1] * vr[1][2 * jj + 1] +
                   att[h * 4 + 2] * vr[2][2 * jj + 1] + att[h * 4 + 3] * vr[3][2 * jj + 1];
        res[jj] = pack2(lo, hf);
      }
      uint4 u = {res[0], res[1], res[2], res[3]};
      oaf[h * 4 + dw] = *reinterpret_cast<bf16x8*>(&u);
    }
  }
  __syncthreads();   // Wbuf[0] ready

  // ---- output GEMM: 8 Wo slices, double-buffered ----
#pragma unroll
  for (int so = 0; so < 8; ++so) {
    if (so < 7) stage_slice(Wall, Wbuf[(so + 1) & 1], 25 + so, w, lane);
    f32x16 acc = gemm_lds(Wbuf[so & 1], oaf, lane);
    if (valid) {
#pragma unroll
      for (int q = 0; q < 4; ++q) {
        int c0 = so * 32 + q * 8 + hi5 * 4;
        float4 b4 = *reinterpret_cast<const float4*>(bo + c0);
        float4 o = {acc[4 * q] + b4.x, acc[4 * q + 1] + b4.y,
                    acc[4 * q + 2] + b4.z, acc[4 * q + 3] + b4.w};
        *reinterpret_cast<float4*>(out + (size_t)n * CC + c0) = o;
      }
    }
    __syncthreads();
  }
}

// ---------------------------------------------------------------------------
extern "C" void kernel_launch(void* const* d_in, const int* in_sizes, int n_in,
                              void* d_out, int out_size, void* d_ws, size_t ws_size,
                              hipStream_t stream) {
  const float* x  = (const float*)d_in[0];
  const int* batch = (const int*)d_in[1];
  const float* Wq = (const float*)d_in[2];
  const float* bq = (const float*)d_in[3];
  const float* Wk = (const float*)d_in[4];
  const float* bk = (const float*)d_in[5];
  const float* Wv = (const float*)d_in[6];
  const float* bv = (const float*)d_in[7];
  const float* Wo = (const float*)d_in[8];
  const float* bo = (const float*)d_in[9];

  char* ws = (char*)d_ws;
  u16*   Wall      = (u16*)ws;                               //   524,288 B (32 slices)
  int*   seg_start = (int*)(ws + 524288);                    //     2,052 B
  float* seg_max   = (float*)(ws + 528384);                  //    32,768 B
  float* seg_sum   = (float*)(ws + 561152);                  //    32,768 B
  float* scores    = (float*)(ws + 593920);                  // 12,800,000 B
  u16*   v_bf      = (u16*)(ws + 13393920);                  // 102,400,000 B

  float* out = (float*)d_out;
  float* att_mean = out + (size_t)NN * CC;

  const int NB = (NN + 127) / 128;   // 1563 blocks of 128 nodes

  prep_kernel<<<1024, 256, 0, stream>>>(Wq, Wk, Wv, Wo, Wall);
  seg_bounds_kernel<<<(NN + 255) / 256, 256, 0, stream>>>(batch, seg_start, NN);
  qkv_scores_kernel<<<NB, 256, 0, stream>>>(x, Wall, bq, bk, bv, v_bf, scores);
  seg_softmax_kernel<<<NG, 256, 0, stream>>>(scores, seg_start, seg_max, seg_sum);
  out_kernel<<<NB, 256, 0, stream>>>(v_bf, scores, batch, seg_max, seg_sum,
                                     Wall, bo, out, att_mean);
}